// Round 15
// baseline (622.151 us; speedup 1.0000x reference)
//
#include <hip/hip_runtime.h>
#include <hip/hip_bf16.h>
#include <math.h>

#define B_  2048
#define E_  64
#define H_  512
#define T_  20

typedef _Float16 half8 __attribute__((ext_vector_type(8)));
typedef __attribute__((ext_vector_type(4))) float f32x4;
typedef unsigned long long u64;

#define mf16(a, b, c) __builtin_amdgcn_mfma_f32_16x16x32_f16(a, b, c, 0, 0, 0)

__device__ __forceinline__ float sigmoidf_(float x) {
  return 1.0f / (1.0f + __expf(-x));
}
__device__ __forceinline__ float tanh_fast(float x) {
  float e = __expf(2.0f * x);
  return 1.0f - 2.0f / (e + 1.0f);
}

// ---------------------------------------------------------------------------
// Parallel stable counting sort + inverse perm + zero flag areas (4096 ints).
// ---------------------------------------------------------------------------
__global__ __launch_bounds__(256) void k_setup(const int* __restrict__ data,
                                               const int* __restrict__ st,
                                               int* __restrict__ perm,
                                               int* __restrict__ iperm,
                                               int* __restrict__ Mt,
                                               int* __restrict__ flags) {
  __shared__ int lens[B_];
  __shared__ int hist[256][22];
  __shared__ int sub[16][22];
  __shared__ int subpre[16][22];
  __shared__ int cnt[32];
  __shared__ int offs[32];
  int tid = threadIdx.x;

  #pragma unroll
  for (int i = 0; i < 16; ++i) flags[tid * 16 + i] = 0;

  #pragma unroll
  for (int q = 0; q < 8; ++q) {
    int i = tid * 8 + q;
    lens[i] = st[data[i] * (T_ + 1) + T_];
  }
  #pragma unroll
  for (int L = 0; L < 22; ++L) hist[tid][L] = 0;
  #pragma unroll
  for (int q = 0; q < 8; ++q) hist[tid][lens[tid * 8 + q]]++;
  __syncthreads();

  for (int q = tid; q < 16 * 21; q += 256) {
    int g = q / 21, L = q % 21;
    int run = 0;
    for (int j = 0; j < 16; ++j) {
      int v = hist[g * 16 + j][L];
      hist[g * 16 + j][L] = run;
      run += v;
    }
    sub[g][L] = run;
  }
  __syncthreads();
  if (tid < 21) {
    int run = 0;
    for (int g = 0; g < 16; ++g) { subpre[g][tid] = run; run += sub[g][tid]; }
    cnt[tid] = run;
  }
  __syncthreads();
  if (tid <= 20) {
    int s = 0;
    for (int L = tid + 1; L <= 20; ++L) s += cnt[L];
    offs[tid] = s;
  }
  __syncthreads();
  if (tid < T_) Mt[tid] = offs[tid];
  if (tid >= T_ && tid < 32) Mt[tid] = 0;

  int g = tid >> 4;
  #pragma unroll
  for (int q = 0; q < 8; ++q) {
    int i = tid * 8 + q;
    int L = lens[i];
    int rk = subpre[g][L] + hist[tid][L];
    hist[tid][L] += 1;
    perm[offs[L] + rk] = i;
  }
  __syncthreads();
  #pragma unroll
  for (int q = 0; q < 8; ++q) {
    int i = tid * 8 + q;
    iperm[perm[i]] = i;
  }
}

__global__ void k_schars(const int* __restrict__ data, const int* __restrict__ st,
                         const int* __restrict__ perm, int* __restrict__ schars_T) {
  int idx = blockIdx.x * 256 + threadIdx.x;
  if (idx >= B_ * T_) return;
  int t = idx >> 11;
  int j = idx & (B_ - 1);
  schars_T[idx] = st[data[perm[j]] * (T_ + 1) + t];
}

// W -> fp16 fragment-packed (18-chunk r8 layout)
__global__ void k_wconv(const float* __restrict__ W_ih, const float* __restrict__ W_hh,
                        _Float16* __restrict__ Wp) {
  int idx = blockIdx.x * 256 + threadIdx.x;
  if (idx >= 8 * 18 * 12 * 512) return;
  int e = idx & 7;
  int l = (idx >> 3) & 63;
  int rest = idx >> 9;
  int g = rest % 3;  rest /= 3;
  int w = rest & 3;  rest >>= 2;
  int c = rest % 18;
  int cb = rest / 18;
  int grow = g * H_ + cb * 64 + w * 16 + (l & 15);
  int k = c * 32 + (l >> 4) * 8 + e;
  float v = (k < E_) ? W_ih[grow * E_ + k] : W_hh[grow * H_ + (k - E_)];
  Wp[idx] = (_Float16)v;
}

__global__ void k_embconv(const float* __restrict__ emb, _Float16* __restrict__ embp) {
  int idx = blockIdx.x * 256 + threadIdx.x;
  if (idx >= 128 * E_) return;
  embp[idx] = (_Float16)emb[idx];
}

// ---------------------------------------------------------------------------
// r8-exact persistent GRU, 4-way visible ablation.
// MODE 0: real.
// MODE 1: NO store path (no h-stores, no vmcnt drain); keep loads+spin+flag.
// MODE 2: NO load path (sb=0); keep stores+drain+spin+flag.
// MODE 3: floor — no global traffic, no flags/spins; LDS+MFMA+epilogue only.
// ---------------------------------------------------------------------------
template <int MODE>
__global__ __launch_bounds__(256, 1) void k_gru(
    const int* __restrict__ Mt, const int* __restrict__ schars_T,
    const _Float16* __restrict__ embp, const _Float16* __restrict__ Wp,
    const float* __restrict__ b_ih, const float* __restrict__ b_hh,
    _Float16* __restrict__ hq0, _Float16* __restrict__ hq1,
    const int* __restrict__ iperm, float* __restrict__ out,
    int* __restrict__ bar) {
  __shared__ __attribute__((aligned(16))) _Float16 As[64][512];   // 64 KB
  __shared__ __attribute__((aligned(16))) _Float16 Hs[64][68];    // 8.7 KB

  int bid = blockIdx.x;
  int rb = bid & 31, cb = bid >> 5;
  int m0 = rb * 64;
  int tid = threadIdx.x;
  int w = tid >> 6;
  int l = tid & 63;
  int ln = l & 15, kc = l >> 4;

  half8 wfr[54];
  const _Float16* wsrc = Wp + ((size_t)(cb * 18) * 12 + w * 3) * 512 + l * 8;
  #pragma unroll
  for (int c = 0; c < 18; ++c) {
    #pragma unroll
    for (int g = 0; g < 3; ++g)
      wfr[c * 3 + g] = *(const half8*)(wsrc + (c * 12 + g) * 512);
  }

  int colg = cb * 64 + w * 16 + ln;
  float br  = b_ih[colg] + b_hh[colg];
  float bz  = b_ih[H_ + colg] + b_hh[H_ + colg];
  float bnx = b_ih[2 * H_ + colg];
  float bnh = b_hh[2 * H_ + colg];

  float hreg[4][4];
  #pragma unroll
  for (int i = 0; i < 4; ++i)
    #pragma unroll
    for (int j = 0; j < 4; ++j) hreg[i][j] = 0.0f;

  int* barp = bar + rb * 32;

  for (int t = 0; t < T_; ++t) {
    int M = Mt[t];
    if (m0 >= M) break;
    const _Float16* hin = (t & 1) ? hq1 : hq0;
    _Float16*       hout = (t & 1) ? hq0 : hq1;

    int ch[4];
    #pragma unroll
    for (int rf = 0; rf < 4; ++rf)
      ch[rf] = schars_T[t * B_ + m0 + rf * 16 + ln];

    u64 sb[16][2];
    if (MODE == 2 || MODE == 3) {
      #pragma unroll
      for (int i = 0; i < 16; ++i) { sb[i][0] = 0; sb[i][1] = 0; }
    }
    if (t > 0) {
      if (MODE != 3) {
        if (tid == 0) {
          int target = 8 * t;
          while (__hip_atomic_load(barp, __ATOMIC_RELAXED, __HIP_MEMORY_SCOPE_AGENT) < target) {}
        }
      }
      __syncthreads();
      if (MODE == 0 || MODE == 1) {
        #pragma unroll
        for (int i = 0; i < 16; ++i) {
          int r = w * 16 + i;
          u64* src = (u64*)(hin + (size_t)(m0 + r) * H_) + ((l ^ (i & 7)) << 1);
          sb[i][0] = __hip_atomic_load(src, __ATOMIC_RELAXED, __HIP_MEMORY_SCOPE_AGENT);
          sb[i][1] = __hip_atomic_load(src + 1, __ATOMIC_RELAXED, __HIP_MEMORY_SCOPE_AGENT);
        }
      }
    }

    f32x4 accr[4], accz[4], accnx[4], accnh[4];
    #pragma unroll
    for (int i = 0; i < 4; ++i) {
      accr[i] = (f32x4){0.f, 0.f, 0.f, 0.f};
      accz[i] = (f32x4){0.f, 0.f, 0.f, 0.f};
      accnx[i] = (f32x4){0.f, 0.f, 0.f, 0.f};
      accnh[i] = (f32x4){0.f, 0.f, 0.f, 0.f};
    }

    #pragma unroll
    for (int rf = 0; rf < 4; ++rf) {
      const _Float16* ep = embp + ch[rf] * E_ + kc * 8;
      half8 a0 = *(const half8*)ep;
      half8 a1 = *(const half8*)(ep + 32);
      accr[rf]  = mf16(a0, wfr[0], accr[rf]);
      accz[rf]  = mf16(a0, wfr[1], accz[rf]);
      accnx[rf] = mf16(a0, wfr[2], accnx[rf]);
      accr[rf]  = mf16(a1, wfr[3], accr[rf]);
      accz[rf]  = mf16(a1, wfr[4], accz[rf]);
      accnx[rf] = mf16(a1, wfr[5], accnx[rf]);
    }

    if (t > 0) {
      #pragma unroll
      for (int i = 0; i < 16; ++i) {
        int r = w * 16 + i;
        u64* dp = (u64*)&As[r][l * 8];
        dp[0] = sb[i][0];
        dp[1] = sb[i][1];
      }
    }
    __syncthreads();

    if (t > 0) {
      const _Float16* asb = &As[0][0];
      #pragma unroll
      for (int chk = 0; chk < 16; ++chk) {
        #pragma unroll
        for (int rf = 0; rf < 4; ++rf) {
          int r = rf * 16 + ln;
          half8 af = *(const half8*)(asb + r * 512 + (((chk * 4 + kc) ^ (ln & 7)) << 3));
          accr[rf]  = mf16(af, wfr[(chk + 2) * 3 + 0], accr[rf]);
          accz[rf]  = mf16(af, wfr[(chk + 2) * 3 + 1], accz[rf]);
          accnh[rf] = mf16(af, wfr[(chk + 2) * 3 + 2], accnh[rf]);
        }
      }
    }

    #pragma unroll
    for (int rf = 0; rf < 4; ++rf) {
      #pragma unroll
      for (int q = 0; q < 4; ++q) {
        int row_l = rf * 16 + kc * 4 + q;
        if (m0 + row_l < M) {
          float r_ = sigmoidf_(accr[rf][q] + br);
          float z_ = sigmoidf_(accz[rf][q] + bz);
          float n_ = tanh_fast(accnx[rf][q] + bnx + r_ * (accnh[rf][q] + bnh));
          float hnew = (1.0f - z_) * n_ + z_ * hreg[rf][q];
          hreg[rf][q] = hnew;
          Hs[row_l][w * 16 + ln] = (_Float16)hnew;
        }
      }
    }
    __syncthreads();

    if (MODE == 0 || MODE == 2) {
      // full store path: coalesced agent stores + drain
      #pragma unroll
      for (int j = 0; j < 4; ++j) {
        int c = tid + 256 * j;
        int row_l = c >> 4;
        int coff = (c & 15) * 4;
        if (m0 + row_l < M) {
          u64 v = *(const u64*)&Hs[row_l][coff];
          __hip_atomic_store((u64*)(hout + (size_t)(m0 + row_l) * H_ + cb * 64 + coff),
                             v, __ATOMIC_RELAXED, __HIP_MEMORY_SCOPE_AGENT);
        }
      }
      asm volatile("s_waitcnt vmcnt(0)" ::: "memory");
      __syncthreads();
      if (tid == 0)
        __hip_atomic_fetch_add(barp, 1, __ATOMIC_RELAXED, __HIP_MEMORY_SCOPE_AGENT);
    } else if (MODE == 1) {
      // no store path; keep Hs alive + advance flag (protocol intact)
      #pragma unroll
      for (int j = 0; j < 4; ++j) {
        int c = tid + 256 * j;
        u64 v = *(const u64*)&Hs[c >> 4][(c & 15) * 4];
        asm volatile("" :: "v"(v));
      }
      __syncthreads();
      if (tid == 0)
        __hip_atomic_fetch_add(barp, 1, __ATOMIC_RELAXED, __HIP_MEMORY_SCOPE_AGENT);
    } else {
      // MODE 3 floor: nothing global
      #pragma unroll
      for (int j = 0; j < 4; ++j) {
        int c = tid + 256 * j;
        u64 v = *(const u64*)&Hs[c >> 4][(c & 15) * 4];
        asm volatile("" :: "v"(v));
      }
      __syncthreads();
    }
  }

  #pragma unroll
  for (int rf = 0; rf < 4; ++rf) {
    #pragma unroll
    for (int q = 0; q < 4; ++q) {
      int row = m0 + rf * 16 + kc * 4 + q;
      out[(size_t)iperm[row] * H_ + colg] = hreg[rf][q];
    }
  }
}

extern "C" void kernel_launch(void* const* d_in, const int* in_sizes, int n_in,
                              void* d_out, int out_size, void* d_ws, size_t ws_size,
                              hipStream_t stream) {
  const int*   data = (const int*)d_in[0];
  const int*   st   = (const int*)d_in[1];
  const float* emb  = (const float*)d_in[2];
  const float* W_ih = (const float*)d_in[3];
  const float* W_hh = (const float*)d_in[4];
  const float* b_ih = (const float*)d_in[5];
  const float* b_hh = (const float*)d_in[6];
  float* out = (float*)d_out;

  // workspace (~14.4 MB)
  _Float16* hq0  = (_Float16*)d_ws;
  _Float16* hq1  = hq0 + B_ * H_;
  _Float16* Wp   = hq1 + B_ * H_;
  _Float16* embp = Wp + 8 * 18 * 12 * 512;
  int* perm   = (int*)(embp + 128 * E_);
  int* iperm  = perm + B_;
  int* Mt     = iperm + B_;
  int* flags  = Mt + 32;                            // 4096 ints (4 areas)
  int* schars = flags + 4096;
  _Float16* sA   = (_Float16*)(schars + B_ * T_);   // scratch h pair
  _Float16* sB   = sA + B_ * H_;
  float*    sout = (float*)(sB + B_ * H_);          // scratch out

  k_setup<<<1, 256, 0, stream>>>(data, st, perm, iperm, Mt, flags);
  k_schars<<<(B_ * T_ + 255) / 256, 256, 0, stream>>>(data, st, perm, schars);
  k_wconv<<<(8 * 18 * 12 * 512 + 255) / 256, 256, 0, stream>>>(W_ih, W_hh, Wp);
  k_embconv<<<(128 * E_ + 255) / 256, 256, 0, stream>>>(emb, embp);

  // M0 real
  k_gru<0><<<dim3(256), dim3(256), 0, stream>>>(Mt, schars, embp, Wp, b_ih, b_hh,
                                                hq0, hq1, iperm, out, flags);
  // M1 no-store-path
  k_gru<1><<<dim3(256), dim3(256), 0, stream>>>(Mt, schars, embp, Wp, b_ih, b_hh,
                                                sA, sB, iperm, sout, flags + 1024);
  // M2 no-load-path
  k_gru<2><<<dim3(256), dim3(256), 0, stream>>>(Mt, schars, embp, Wp, b_ih, b_hh,
                                                sA, sB, iperm, sout, flags + 2048);
  // M3 floor
  k_gru<3><<<dim3(256), dim3(256), 0, stream>>>(Mt, schars, embp, Wp, b_ih, b_hh,
                                                sA, sB, iperm, sout, flags + 3072);
}

// Round 16
// 188.494 us; speedup vs baseline: 3.3006x; 3.3006x over previous
//
#include <hip/hip_runtime.h>
#include <hip/hip_bf16.h>
#include <math.h>

#define B_  2048
#define E_  64
#define H_  512
#define T_  20

typedef _Float16 half8 __attribute__((ext_vector_type(8)));
typedef __attribute__((ext_vector_type(4))) float f32x4;
typedef unsigned long long u64;

#define mf16(a, b, c) __builtin_amdgcn_mfma_f32_16x16x32_f16(a, b, c, 0, 0, 0)

__device__ __forceinline__ float sigmoidf_(float x) {
  return 1.0f / (1.0f + __expf(-x));
}
__device__ __forceinline__ float tanh_fast(float x) {
  float e = __expf(2.0f * x);
  return 1.0f - 2.0f / (e + 1.0f);
}

// ---------------------------------------------------------------------------
// Parallel stable counting sort + inverse perm + zero flag area.
// ---------------------------------------------------------------------------
__global__ __launch_bounds__(256) void k_setup(const int* __restrict__ data,
                                               const int* __restrict__ st,
                                               int* __restrict__ perm,
                                               int* __restrict__ iperm,
                                               int* __restrict__ Mt,
                                               int* __restrict__ flags) {
  __shared__ int lens[B_];
  __shared__ int hist[256][22];
  __shared__ int sub[16][22];
  __shared__ int subpre[16][22];
  __shared__ int cnt[32];
  __shared__ int offs[32];
  int tid = threadIdx.x;

  #pragma unroll
  for (int i = 0; i < 4; ++i) flags[tid * 4 + i] = 0;

  #pragma unroll
  for (int q = 0; q < 8; ++q) {
    int i = tid * 8 + q;
    lens[i] = st[data[i] * (T_ + 1) + T_];
  }
  #pragma unroll
  for (int L = 0; L < 22; ++L) hist[tid][L] = 0;
  #pragma unroll
  for (int q = 0; q < 8; ++q) hist[tid][lens[tid * 8 + q]]++;
  __syncthreads();

  for (int q = tid; q < 16 * 21; q += 256) {
    int g = q / 21, L = q % 21;
    int run = 0;
    for (int j = 0; j < 16; ++j) {
      int v = hist[g * 16 + j][L];
      hist[g * 16 + j][L] = run;
      run += v;
    }
    sub[g][L] = run;
  }
  __syncthreads();
  if (tid < 21) {
    int run = 0;
    for (int g = 0; g < 16; ++g) { subpre[g][tid] = run; run += sub[g][tid]; }
    cnt[tid] = run;
  }
  __syncthreads();
  if (tid <= 20) {
    int s = 0;
    for (int L = tid + 1; L <= 20; ++L) s += cnt[L];
    offs[tid] = s;
  }
  __syncthreads();
  if (tid < T_) Mt[tid] = offs[tid];
  if (tid >= T_ && tid < 32) Mt[tid] = 0;

  int g = tid >> 4;
  #pragma unroll
  for (int q = 0; q < 8; ++q) {
    int i = tid * 8 + q;
    int L = lens[i];
    int rk = subpre[g][L] + hist[tid][L];
    hist[tid][L] += 1;
    perm[offs[L] + rk] = i;
  }
  __syncthreads();
  #pragma unroll
  for (int q = 0; q < 8; ++q) {
    int i = tid * 8 + q;
    iperm[perm[i]] = i;
  }
}

__global__ void k_schars(const int* __restrict__ data, const int* __restrict__ st,
                         const int* __restrict__ perm, int* __restrict__ schars_T) {
  int idx = blockIdx.x * 256 + threadIdx.x;
  if (idx >= B_ * T_) return;
  int t = idx >> 11;
  int j = idx & (B_ - 1);
  schars_T[idx] = st[data[perm[j]] * (T_ + 1) + t];
}

// W_hh -> fp16 fragment-packed: Wp[(((cb*16+c)*4+wc)*3+g)*512 + l*8 + e]
__global__ void k_wconv(const float* __restrict__ W_hh, _Float16* __restrict__ Wp) {
  int idx = blockIdx.x * 256 + threadIdx.x;
  if (idx >= 8 * 16 * 12 * 512) return;
  int e = idx & 7;
  int l = (idx >> 3) & 63;
  int rest = idx >> 9;
  int g = rest % 3;  rest /= 3;
  int wc = rest & 3; rest >>= 2;
  int c = rest % 16;
  int cb = rest / 16;
  int grow = g * H_ + cb * 64 + wc * 16 + (l & 15);
  int k = c * 32 + (l >> 4) * 8 + e;
  Wp[idx] = (_Float16)W_hh[grow * H_ + k];
}

// embW[c][g*512+col] = emb[c] . W_ih[g*512+col] + b_ih (+ b_hh for r,z)
__global__ __launch_bounds__(256) void k_embw(const float* __restrict__ emb,
                                              const float* __restrict__ W_ih,
                                              const float* __restrict__ b_ih,
                                              const float* __restrict__ b_hh,
                                              float* __restrict__ embW) {
  int c = blockIdx.x;
  int tid = threadIdx.x;
  __shared__ float ev[64];
  if (tid < 64) ev[tid] = emb[c * E_ + tid];
  __syncthreads();
  for (int o = tid; o < 3 * H_; o += 256) {
    float s = b_ih[o];
    if (o < 2 * H_) s += b_hh[o];
    #pragma unroll
    for (int k = 0; k < E_; ++k) s = fmaf(ev[k], W_ih[o * E_ + k], s);
    embW[(size_t)c * (3 * H_) + o] = s;
  }
}

// ---------------------------------------------------------------------------
// Persistent GRU, K-split so W truly fits in registers (no remat).
// 256 blocks x 512 thr (8 waves): wc = w&3 (16-col group), kh = w>>2 (K half,
// 8 h-chunks each). W = 24 frags = 96 VGPR per wave. x-side folded into embW.
// Cross-K reduction via Rs[3][64][68] f32 LDS (aligned f32x4, 2-way banks);
// epilogue split by row halves (kh0: rows 0-31, kh1: rows 32-63).
// Exchange protocol = r8 exact (per-rb flag line, agent u64 load/store,
// vmcnt drain, tid0 spin). As layout/swizzle = r8 exact.
// ---------------------------------------------------------------------------
__global__ __launch_bounds__(512, 1) void k_gru(
    const int* __restrict__ Mt, const int* __restrict__ schars_T,
    const float* __restrict__ embW, const _Float16* __restrict__ Wp,
    const float* __restrict__ b_hh,
    _Float16* __restrict__ hq0, _Float16* __restrict__ hq1,
    const int* __restrict__ iperm, float* __restrict__ out,
    int* __restrict__ bar) {
  __shared__ __attribute__((aligned(16))) _Float16 As[64][512];   // 64 KB
  __shared__ __attribute__((aligned(16))) float    Rs[3][64][68]; // 52.2 KB
  __shared__ __attribute__((aligned(16))) _Float16 Hs[64][68];    // 8.7 KB

  int bid = blockIdx.x;
  int rb = bid & 31, cb = bid >> 5;
  int m0 = rb * 64;
  int tid = threadIdx.x;
  int w  = tid >> 6;          // 0..7
  int wc = w & 3, kh = w >> 2;
  int l  = tid & 63, ln = l & 15, kc = l >> 4;

  // ---- W fragments: this wave's K-half (8 chunks x 3 gates = 96 VGPR) ----
  half8 wfr[24];
  #pragma unroll
  for (int f = 0; f < 8; ++f)
    #pragma unroll
    for (int g = 0; g < 3; ++g)
      wfr[f * 3 + g] = *(const half8*)(Wp +
          (((size_t)(cb * 16 + kh * 8 + f) * 4 + wc) * 3 + g) * 512 + l * 8);

  int colg = cb * 64 + wc * 16 + ln;
  int colw = wc * 16 + ln;
  float bnh = b_hh[2 * H_ + colg];

  float hreg[2][4];
  #pragma unroll
  for (int i = 0; i < 2; ++i)
    #pragma unroll
    for (int j = 0; j < 4; ++j) hreg[i][j] = 0.0f;

  int* barp = bar + rb * 32;

#define EPI(RF, D, ROWB)                                                       \
  {                                                                            \
    f32x4 pr4, pz4, pn4;                                                       \
    if (t > 0) {                                                               \
      pr4 = *(const f32x4*)&Rs[0][colw][(ROWB)];                               \
      pz4 = *(const f32x4*)&Rs[1][colw][(ROWB)];                               \
      pn4 = *(const f32x4*)&Rs[2][colw][(ROWB)];                               \
    } else {                                                                   \
      pr4 = (f32x4){0.f, 0.f, 0.f, 0.f}; pz4 = pr4; pn4 = pr4;                 \
    }                                                                          \
    _Pragma("unroll")                                                          \
    for (int q = 0; q < 4; ++q) {                                              \
      int row_l = (ROWB) + q;                                                  \
      if (m0 + row_l < M) {                                                    \
        int chv = schars_T[t * B_ + m0 + row_l];                               \
        const float* ew = embW + (size_t)chv * (3 * H_) + colg;                \
        float r_ = sigmoidf_(accr[RF][q] + pr4[q] + ew[0]);                    \
        float z_ = sigmoidf_(accz[RF][q] + pz4[q] + ew[H_]);                   \
        float n_ = tanh_fast(ew[2 * H_] + r_ * (accnh[RF][q] + pn4[q] + bnh)); \
        hreg[D][q] = (1.0f - z_) * n_ + z_ * hreg[D][q];                       \
        Hs[row_l][colw] = (_Float16)hreg[D][q];                                \
      }                                                                        \
    }                                                                          \
  }

  for (int t = 0; t < T_; ++t) {
    int M = Mt[t];
    if (m0 >= M) break;
    const _Float16* hin  = (t & 1) ? hq1 : hq0;
    _Float16*       hout = (t & 1) ? hq0 : hq1;

    f32x4 accr[4], accz[4], accnh[4];
    #pragma unroll
    for (int i = 0; i < 4; ++i) {
      accr[i] = (f32x4){0.f, 0.f, 0.f, 0.f};
      accz[i] = (f32x4){0.f, 0.f, 0.f, 0.f};
      accnh[i] = (f32x4){0.f, 0.f, 0.f, 0.f};
    }

    if (t > 0) {
      // ---- wait for cohort flags, then stage h (r8 pattern, 8 rows/wave) --
      if (tid == 0) {
        int target = 8 * t;
        while (__hip_atomic_load(barp, __ATOMIC_RELAXED, __HIP_MEMORY_SCOPE_AGENT) < target) {}
      }
      __syncthreads();
      u64 sb[8][2];
      #pragma unroll
      for (int i = 0; i < 8; ++i) {
        int r = w * 8 + i;
        u64* src = (u64*)(hin + (size_t)(m0 + r) * H_) + ((l ^ (i & 7)) << 1);
        sb[i][0] = __hip_atomic_load(src, __ATOMIC_RELAXED, __HIP_MEMORY_SCOPE_AGENT);
        sb[i][1] = __hip_atomic_load(src + 1, __ATOMIC_RELAXED, __HIP_MEMORY_SCOPE_AGENT);
      }
      #pragma unroll
      for (int i = 0; i < 8; ++i) {
        int r = w * 8 + i;
        u64* dp = (u64*)&As[r][l * 8];
        dp[0] = sb[i][0];
        dp[1] = sb[i][1];
      }
      __syncthreads();

      // ---- MFMA: this wave's 8 K-chunks over all 64 rows ----
      #pragma unroll
      for (int f = 0; f < 8; ++f) {
        int chk = kh * 8 + f;
        #pragma unroll
        for (int rf = 0; rf < 4; ++rf) {
          int r = rf * 16 + ln;
          half8 af = *(const half8*)((const _Float16*)As + r * 512 +
                                     (((chk * 4 + kc) ^ (ln & 7)) << 3));
          accr[rf]  = mf16(af, wfr[f * 3 + 0], accr[rf]);
          accz[rf]  = mf16(af, wfr[f * 3 + 1], accz[rf]);
          accnh[rf] = mf16(af, wfr[f * 3 + 2], accnh[rf]);
        }
      }

      // ---- write partner-half partials (constant indices per branch) ----
      if (kh == 0) {
        *(f32x4*)&Rs[0][colw][32 + kc * 4] = accr[2];
        *(f32x4*)&Rs[1][colw][32 + kc * 4] = accz[2];
        *(f32x4*)&Rs[2][colw][32 + kc * 4] = accnh[2];
        *(f32x4*)&Rs[0][colw][48 + kc * 4] = accr[3];
        *(f32x4*)&Rs[1][colw][48 + kc * 4] = accz[3];
        *(f32x4*)&Rs[2][colw][48 + kc * 4] = accnh[3];
      } else {
        *(f32x4*)&Rs[0][colw][0 + kc * 4]  = accr[0];
        *(f32x4*)&Rs[1][colw][0 + kc * 4]  = accz[0];
        *(f32x4*)&Rs[2][colw][0 + kc * 4]  = accnh[0];
        *(f32x4*)&Rs[0][colw][16 + kc * 4] = accr[1];
        *(f32x4*)&Rs[1][colw][16 + kc * 4] = accz[1];
        *(f32x4*)&Rs[2][colw][16 + kc * 4] = accnh[1];
      }
      __syncthreads();
    }

    // ---- epilogue: own row half (kh0: rows 0-31, kh1: rows 32-63) ----
    if (kh == 0) {
      EPI(0, 0, kc * 4)
      EPI(1, 1, 16 + kc * 4)
    } else {
      EPI(2, 0, 32 + kc * 4)
      EPI(3, 1, 48 + kc * 4)
    }
    __syncthreads();

    // ---- coalesced agent-scope h-out (r8 exact, 2 u64/thread) ----
    #pragma unroll
    for (int j = 0; j < 2; ++j) {
      int c = tid + 512 * j;
      int row_l = c >> 4;
      int coff = (c & 15) * 4;
      if (m0 + row_l < M) {
        u64 v = *(const u64*)&Hs[row_l][coff];
        __hip_atomic_store((u64*)(hout + (size_t)(m0 + row_l) * H_ + cb * 64 + coff),
                           v, __ATOMIC_RELAXED, __HIP_MEMORY_SCOPE_AGENT);
      }
    }
    asm volatile("s_waitcnt vmcnt(0)" ::: "memory");
    __syncthreads();
    if (tid == 0)
      __hip_atomic_fetch_add(barp, 1, __ATOMIC_RELAXED, __HIP_MEMORY_SCOPE_AGENT);
  }
#undef EPI

  // ---- final state -> out[iperm[row]] (reference returns ht[perm]) ----
  #pragma unroll
  for (int d = 0; d < 2; ++d) {
    #pragma unroll
    for (int q = 0; q < 4; ++q) {
      int row = m0 + (kh * 32 + d * 16) + kc * 4 + q;
      out[(size_t)iperm[row] * H_ + colg] = hreg[d][q];
    }
  }
}

extern "C" void kernel_launch(void* const* d_in, const int* in_sizes, int n_in,
                              void* d_out, int out_size, void* d_ws, size_t ws_size,
                              hipStream_t stream) {
  const int*   data = (const int*)d_in[0];
  const int*   st   = (const int*)d_in[1];
  const float* emb  = (const float*)d_in[2];
  const float* W_ih = (const float*)d_in[3];
  const float* W_hh = (const float*)d_in[4];
  const float* b_ih = (const float*)d_in[5];
  const float* b_hh = (const float*)d_in[6];
  float* out = (float*)d_out;

  // workspace (~7 MB)
  _Float16* hq0  = (_Float16*)d_ws;                 // B*H fp16
  _Float16* hq1  = hq0 + B_ * H_;                   // B*H fp16
  _Float16* Wp   = hq1 + B_ * H_;                   // 786432 halfs
  float*    embW = (float*)(Wp + 8 * 16 * 12 * 512);// 128*1536 fp32
  int* perm   = (int*)(embW + 128 * 3 * H_);
  int* iperm  = perm + B_;
  int* Mt     = iperm + B_;
  int* flags  = Mt + 32;                            // 1024 ints
  int* schars = flags + 1024;

  k_setup<<<1, 256, 0, stream>>>(data, st, perm, iperm, Mt, flags);
  k_schars<<<(B_ * T_ + 255) / 256, 256, 0, stream>>>(data, st, perm, schars);
  k_wconv<<<(8 * 16 * 12 * 512 + 255) / 256, 256, 0, stream>>>(W_hh, Wp);
  k_embw<<<128, 256, 0, stream>>>(emb, W_ih, b_ih, b_hh, embW);

  k_gru<<<dim3(256), dim3(512), 0, stream>>>(Mt, schars, embW, Wp, b_hh,
                                             hq0, hq1, iperm, out, flags);
}